// Round 1
// 391.583 us; speedup vs baseline: 1.0492x; 1.0492x over previous
//
#include <hip/hip_runtime.h>

#define NN 100000
#define EE 1600000
#define NCOPY 8

typedef short bf16x8 __attribute__((ext_vector_type(8)));
typedef float floatx4 __attribute__((ext_vector_type(4)));

__device__ __forceinline__ unsigned short f2bf(float f) {
    unsigned int u = __float_as_uint(f);
    u = (u + 0x7FFF + ((u >> 16) & 1)) >> 16;   // round-to-nearest-even
    return (unsigned short)u;
}
__device__ __forceinline__ float bf2f_lo(unsigned int packed) {
    return __uint_as_float(packed << 16);
}
__device__ __forceinline__ float bf2f_hi(unsigned int packed) {
    return __uint_as_float(packed & 0xFFFF0000u);
}

// ---------------- init: zero cntp (782 blocks) + weight cvt (40 blocks) ------

#define ZB 782   // (NCOPY*NN/4 + 255)/256

__global__ __launch_bounds__(256) void k_init(int4* __restrict__ cntp4,
                                              const float* __restrict__ W1,
                                              const float* __restrict__ W2,
                                              const float* __restrict__ WL,
                                              unsigned short* __restrict__ W1b,
                                              unsigned short* __restrict__ W2b,
                                              unsigned short* __restrict__ WLb) {
    if (blockIdx.x < ZB) {
        int i = blockIdx.x * 256 + threadIdx.x;
        if (i < NCOPY * NN / 4) cntp4[i] = make_int4(0, 0, 0, 0);
        return;
    }
    int i = (blockIdx.x - ZB) * 256 + threadIdx.x;   // quad index
    const float* src; unsigned short* dst; int off;
    if (i < 4096)       { src = W1; dst = W1b; off = i; }
    else if (i < 8192)  { src = W2; dst = W2b; off = i - 4096; }
    else if (i < 10240) { src = WL; dst = WLb; off = i - 8192; }
    else return;
    float4 f = ((const float4*)src)[off];
    unsigned short r0 = f2bf(f.x), r1 = f2bf(f.y), r2 = f2bf(f.z), r3 = f2bf(f.w);
    ((ushort2*)dst)[off * 2]     = make_ushort2(r0, r1);
    ((ushort2*)dst)[off * 2 + 1] = make_ushort2(r2, r3);
}

// Pass 1: rank within XCD-local copy (p = blockIdx&7).
__global__ void k_count_rank8(const int* __restrict__ dst, int* __restrict__ cntp,
                              int* __restrict__ rank) {
    int e8 = (blockIdx.x * 256 + threadIdx.x) * 8;
    int* c = cntp + (blockIdx.x & (NCOPY - 1)) * NN;
    if (e8 < EE) {   // EE % 8 == 0
        int4 d0 = *(const int4*)&dst[e8];
        int4 d1 = *(const int4*)&dst[e8 + 4];
        int4 r0, r1;
        r0.x = atomicAdd(&c[d0.x], 1);
        r0.y = atomicAdd(&c[d0.y], 1);
        r0.z = atomicAdd(&c[d0.z], 1);
        r0.w = atomicAdd(&c[d0.w], 1);
        r1.x = atomicAdd(&c[d1.x], 1);
        r1.y = atomicAdd(&c[d1.y], 1);
        r1.z = atomicAdd(&c[d1.z], 1);
        r1.w = atomicAdd(&c[d1.w], 1);
        *(int4*)&rank[e8]     = r0;
        *(int4*)&rank[e8 + 4] = r1;
    }
}

// scan1: per-node copy-prefix across the 8 cntp copies + 1024-block exclusive
// scan of totals; block totals -> S.
__global__ __launch_bounds__(1024) void k_scan1(int* __restrict__ cntp,
                                                int* __restrict__ cnt,
                                                int* __restrict__ row_ptr,
                                                int* __restrict__ S) {
    __shared__ int sh[1024];
    int tid = threadIdx.x;
    int i = blockIdx.x * 1024 + tid;
    int v = 0;
    if (i < NN) {
        int s = 0;
#pragma unroll
        for (int p = 0; p < NCOPY; p++) {
            int t = cntp[p * NN + i];
            cntp[p * NN + i] = s;    // within-node prefix across copies
            s += t;
        }
        cnt[i] = s;
        v = s;
    }
    sh[tid] = v;
    __syncthreads();
    for (int off = 1; off < 1024; off <<= 1) {
        int t = (tid >= off) ? sh[tid - off] : 0;
        __syncthreads();
        sh[tid] += t;
        __syncthreads();
    }
    if (i < NN) row_ptr[i] = sh[tid] - v;       // exclusive
    if (tid == 1023) S[blockIdx.x] = sh[tid];   // block total
}

// scan2+scan3 fused: every block redundantly scans the 98 block totals in LDS,
// then finalizes rc/dis and folds absolute row_ptr into the 8 copy cursors.
__global__ __launch_bounds__(256) void k_scan23(const int* __restrict__ row_ptr,
                                                int2* __restrict__ rc,
                                                const int* __restrict__ Sraw, int nb,
                                                const int* __restrict__ cnt,
                                                float* __restrict__ dis,
                                                int* __restrict__ cntp,
                                                unsigned int* __restrict__ Azero,
                                                unsigned int* __restrict__ A2zero) {
    __shared__ int sh[128];
    int tid = threadIdx.x;
    int v = 0;
    if (tid < 128) {
        v = (tid < nb) ? Sraw[tid] : 0;
        sh[tid] = v;
    }
    __syncthreads();
    for (int off = 1; off < 128; off <<= 1) {
        int t = 0;
        if (tid < 128 && tid >= off) t = sh[tid - off];
        __syncthreads();
        if (tid < 128) sh[tid] += t;
        __syncthreads();
    }
    int excl = 0;
    if (tid < 128) excl = sh[tid] - v;
    __syncthreads();
    if (tid < 128) sh[tid] = excl;
    __syncthreads();

    int i = blockIdx.x * 256 + tid;
    if (i < NN) {
        int c = cnt[i];
        int r = row_ptr[i] + sh[i >> 10];
        rc[i] = make_int2(r, c);
        dis[i] = rsqrtf((float)(c + 1));
#pragma unroll
        for (int p = 0; p < NCOPY; p++) cntp[p * NN + i] += r;  // absolute base cursors
    }
    if (blockIdx.x == 0 && tid < 64) { Azero[tid] = 0; A2zero[tid] = 0; }  // zero rows
}

// ---------------- MFMA GEMM body (used by packed gemm1) ----------------------
// C[M,F] = A[M,128] @ W[F,128].T, optional row scale (folds dis[src] in).
// Layouts (learn_hip m89): A[m=lane&15][k=quad*8+j], B[n=lane&15][k=quad*8+j],
// C/D col=lane&15 row=quad*4+reg.

template <int F, bool A_F32, bool OUT_BF16, bool SCALE>
__device__ __forceinline__ void gemm_body(int blk, int tid,
                                          const void* __restrict__ A_,
                                          const unsigned short* __restrict__ Wb,
                                          const float* __restrict__ bias,
                                          const float* __restrict__ scale,
                                          void* __restrict__ Cout, int M) {
    int wave = tid >> 6, lane = tid & 63;
    int quad = lane >> 4, r16 = lane & 15;
    int node0 = blk * 64 + wave * 16;

    int arow = node0 + r16;
    if (arow >= M) arow = M - 1;                 // clamp read; stores guarded

    bf16x8 af[4];
    if (A_F32) {
        const float* Ap = (const float*)A_ + (size_t)arow * 128 + quad * 8;
#pragma unroll
        for (int ks = 0; ks < 4; ks++) {
            float4 x0 = *(const float4*)(Ap + ks * 32);
            float4 x1 = *(const float4*)(Ap + ks * 32 + 4);
            bf16x8 t;
            t[0] = (short)f2bf(x0.x); t[1] = (short)f2bf(x0.y);
            t[2] = (short)f2bf(x0.z); t[3] = (short)f2bf(x0.w);
            t[4] = (short)f2bf(x1.x); t[5] = (short)f2bf(x1.y);
            t[6] = (short)f2bf(x1.z); t[7] = (short)f2bf(x1.w);
            af[ks] = t;
        }
    } else {
        const unsigned short* Ap = (const unsigned short*)A_ + (size_t)arow * 128 + quad * 8;
#pragma unroll
        for (int ks = 0; ks < 4; ks++) af[ks] = *(const bf16x8*)(Ap + ks * 32);
    }

    float dsc[4];
#pragma unroll
    for (int rg = 0; rg < 4; rg++) {
        int node = node0 + quad * 4 + rg;
        dsc[rg] = SCALE ? scale[(node < M) ? node : (M - 1)] : 1.f;
    }

    constexpr int NFT = F / 16;
#pragma unroll
    for (int ft = 0; ft < NFT; ft++) {
        int f = ft * 16 + r16;
        const unsigned short* Bp = Wb + (size_t)f * 128 + quad * 8;
        floatx4 acc = {0.f, 0.f, 0.f, 0.f};
#pragma unroll
        for (int ks = 0; ks < 4; ks++) {
            bf16x8 bfr = *(const bf16x8*)(Bp + ks * 32);
            acc = __builtin_amdgcn_mfma_f32_16x16x32_bf16(af[ks], bfr, acc, 0, 0, 0);
        }
        float bv = bias ? bias[f] : 0.f;
#pragma unroll
        for (int rg = 0; rg < 4; rg++) {
            int node = node0 + quad * 4 + rg;
            if (node < M) {
                float o = acc[rg];
                if (SCALE) o *= dsc[rg];
                o += bv;
                if (OUT_BF16)
                    ((unsigned short*)Cout)[(size_t)node * F + f] = f2bf(o);
                else
                    ((float*)Cout)[(size_t)node * F + f] = o;
            }
        }
    }
}

// ---------------- packed: fill4 (blocks 0..781) + GEMM1 (rest) ---------------

#define FB 782   // fill blocks

__global__ __launch_bounds__(256) void k_pack1(const int* __restrict__ src,
                                               const int* __restrict__ dst,
                                               const int* __restrict__ rank,
                                               const int* __restrict__ cntp,
                                               int* __restrict__ csr,
                                               const float* __restrict__ x,
                                               const unsigned short* __restrict__ W1b,
                                               const float* __restrict__ dis,
                                               unsigned short* __restrict__ A) {
    if (blockIdx.x < FB) {
        int e8 = (blockIdx.x * 256 + threadIdx.x) * 8;
        const int* c = cntp + (blockIdx.x & (NCOPY - 1)) * NN;
        if (e8 < EE) {
            int4 s0 = *(const int4*)&src[e8];
            int4 s1 = *(const int4*)&src[e8 + 4];
            int4 d0 = *(const int4*)&dst[e8];
            int4 d1 = *(const int4*)&dst[e8 + 4];
            int4 r0 = *(const int4*)&rank[e8];
            int4 r1 = *(const int4*)&rank[e8 + 4];
            csr[c[d0.x] + r0.x] = s0.x;
            csr[c[d0.y] + r0.y] = s0.y;
            csr[c[d0.z] + r0.z] = s0.z;
            csr[c[d0.w] + r0.w] = s0.w;
            csr[c[d1.x] + r1.x] = s1.x;
            csr[c[d1.y] + r1.y] = s1.y;
            csr[c[d1.z] + r1.z] = s1.z;
            csr[c[d1.w] + r1.w] = s1.w;
        }
        return;
    }
    gemm_body<128, true, true, true>(blockIdx.x - FB, threadIdx.x, x, W1b,
                                     nullptr, dis, A, NN);
}

// ---------------- fused aggregation + GEMM -----------------------------------
// One wave owns 16 nodes. Phase A: per node, R7-proven gather loop (4 gathers
// in flight, 16 lanes x 8 features). After the butterfly reduce every lane
// holds the full sum, so lane-group g KEEPS the acc of node (ni&3)==g; every
// 4 nodes one batched tail uses all 64 lanes (4 nodes x 16 octets) -> tail
// VALU and mv/res loads are 1/4 of the per-node-redundant version. h goes to
// a padded LDS tile (and optionally global). Phase B: wave-local MFMA GEMM
// from LDS (m2' = h@W2.T*dis, or head out = h@WL.T+bl) — no h round-trip,
// MFMA runs in the shadow of other waves' gathers.

template <bool RES_F32, int F, bool OUT_BF16, bool GSCALE, bool WRITE_H>
__global__ __launch_bounds__(128) void k_aggemm(const unsigned short* __restrict__ m,
                                                const int2* __restrict__ rc,
                                                const int* __restrict__ csr,
                                                const float* __restrict__ dis,
                                                const float* __restrict__ bias,
                                                const void* __restrict__ res_,
                                                unsigned short* __restrict__ hout,
                                                const unsigned short* __restrict__ Wb,
                                                const float* __restrict__ gbias,
                                                void* __restrict__ gout) {
    __shared__ unsigned short hsh[2][16][136];   // +8 pad: 2-way max on frag reads
    int tid = threadIdx.x;
    int w = tid >> 6, lane = tid & 63;
    int wbase = blockIdx.x * 32 + w * 16;
    int g = lane >> 4;            // edge slot / node-in-batch
    int fl = (lane & 15) * 8;     // 8 features per lane
    const char* mb2 = (const char*)m + fl * 2;   // 32-bit row offsets: s<<8

    float keep[8];
#pragma unroll
    for (int j = 0; j < 8; j++) keep[j] = 0.f;

    for (int ni = 0; ni < 16; ++ni) {
        int v = wbase + ni;
        float acc[8];
#pragma unroll
        for (int j = 0; j < 8; j++) acc[j] = 0.f;
        int2 rcv = (v < NN) ? rc[v] : make_int2(0, 0);
        int start = rcv.x;
        int c = rcv.y;

        for (int base = 0; base < c; base += 16) {
            int i0 = base + g, i1 = base + 4 + g, i2 = base + 8 + g, i3 = base + 12 + g;
            bool p0 = i0 < c, p1 = i1 < c, p2 = i2 < c, p3 = i3 < c;
            int s0 = csr[start + (p0 ? i0 : 0)];
            int s1 = csr[start + (p1 ? i1 : 0)];
            int s2 = csr[start + (p2 ? i2 : 0)];
            int s3 = csr[start + (p3 ? i3 : 0)];
            if (!p0) s0 = NN;          // zero row
            if (!p1) s1 = NN;
            if (!p2) s2 = NN;
            if (!p3) s3 = NN;
            uint4 r0 = *(const uint4*)(mb2 + (s0 << 8));
            uint4 r1 = *(const uint4*)(mb2 + (s1 << 8));
            uint4 r2 = *(const uint4*)(mb2 + (s2 << 8));
            uint4 r3 = *(const uint4*)(mb2 + (s3 << 8));
#pragma unroll
            for (int q = 0; q < 4; q++) {
                uint4 r = q == 0 ? r0 : q == 1 ? r1 : q == 2 ? r2 : r3;
                acc[0] += bf2f_lo(r.x);
                acc[1] += bf2f_hi(r.x);
                acc[2] += bf2f_lo(r.y);
                acc[3] += bf2f_hi(r.y);
                acc[4] += bf2f_lo(r.z);
                acc[5] += bf2f_hi(r.z);
                acc[6] += bf2f_lo(r.w);
                acc[7] += bf2f_hi(r.w);
            }
        }

        // butterfly reduce across the 4 lane-groups: every lane has full sum
#pragma unroll
        for (int j = 0; j < 8; j++) {
            acc[j] += __shfl_xor(acc[j], 32);
            acc[j] += __shfl_xor(acc[j], 16);
        }
        // lane-group g keeps the node whose batch slot matches it
        bool mine = (g == (ni & 3));
#pragma unroll
        for (int j = 0; j < 8; j++) keep[j] = mine ? acc[j] : keep[j];

        if ((ni & 3) == 3) {
            // batched tail: 64 lanes = 4 nodes x 16 feature-octets
            int nib = (ni & ~3) + g;
            int vv = wbase + nib;
            bool valid = vv < NN;
            int vr = valid ? vv : NN - 1;
            float dv = dis[vr];
            uint4 mv = *(const uint4*)(m + (size_t)vr * 128 + fl);
            float4 q0 = *(const float4*)&bias[fl];
            float4 q1 = *(const float4*)&bias[fl + 4];
            float bb[8] = {q0.x, q0.y, q0.z, q0.w, q1.x, q1.y, q1.z, q1.w};
            float mvf[8] = {bf2f_lo(mv.x), bf2f_hi(mv.x), bf2f_lo(mv.y), bf2f_hi(mv.y),
                            bf2f_lo(mv.z), bf2f_hi(mv.z), bf2f_lo(mv.w), bf2f_hi(mv.w)};
            float rr[8];
            if (RES_F32) {
                const float* rp = (const float*)res_ + (size_t)vr * 128 + fl;
                float4 a0 = *(const float4*)rp;
                float4 a1 = *(const float4*)(rp + 4);
                rr[0] = a0.x; rr[1] = a0.y; rr[2] = a0.z; rr[3] = a0.w;
                rr[4] = a1.x; rr[5] = a1.y; rr[6] = a1.z; rr[7] = a1.w;
            } else {
                uint4 rv = *(const uint4*)((const unsigned short*)res_ + (size_t)vr * 128 + fl);
                rr[0] = bf2f_lo(rv.x); rr[1] = bf2f_hi(rv.x);
                rr[2] = bf2f_lo(rv.y); rr[3] = bf2f_hi(rv.y);
                rr[4] = bf2f_lo(rv.z); rr[5] = bf2f_hi(rv.z);
                rr[6] = bf2f_lo(rv.w); rr[7] = bf2f_hi(rv.w);
            }
            unsigned short po[8];
#pragma unroll
            for (int j = 0; j < 8; j++) {
                float sum = keep[j] + mvf[j];
                float t = fmaxf(fmaf(sum, dv, bb[j]), 0.f) + rr[j];
                if (!valid) t = 0.f;
                po[j] = f2bf(t);
            }
            uint4 o;
            o.x = (unsigned)po[0] | ((unsigned)po[1] << 16);
            o.y = (unsigned)po[2] | ((unsigned)po[3] << 16);
            o.z = (unsigned)po[4] | ((unsigned)po[5] << 16);
            o.w = (unsigned)po[6] | ((unsigned)po[7] << 16);
            *(uint4*)&hsh[w][nib][fl] = o;
            if (WRITE_H && valid) *(uint4*)&hout[(size_t)vv * 128 + fl] = o;
        }
    }

    __builtin_amdgcn_wave_barrier();                 // wave-local LDS: no __syncthreads
    asm volatile("s_waitcnt lgkmcnt(0)" ::: "memory");

    // Phase B: C[wbase..wbase+15][0..F) = hsh[w] @ Wb.T (+scale/bias)
    int quad = g, r16 = lane & 15;
    bf16x8 af[4];
    const unsigned short* Ap = &hsh[w][r16][quad * 8];
#pragma unroll
    for (int ks = 0; ks < 4; ks++) af[ks] = *(const bf16x8*)(Ap + ks * 32);
    float dsc[4];
#pragma unroll
    for (int rg = 0; rg < 4; rg++) {
        int node = wbase + quad * 4 + rg;
        dsc[rg] = GSCALE ? dis[(node < NN) ? node : (NN - 1)] : 1.f;
    }
    constexpr int NFT = F / 16;
#pragma unroll
    for (int ft = 0; ft < NFT; ft++) {
        int f = ft * 16 + r16;
        const unsigned short* Bp = Wb + (size_t)f * 128 + quad * 8;
        floatx4 a4 = {0.f, 0.f, 0.f, 0.f};
#pragma unroll
        for (int ks = 0; ks < 4; ks++) {
            bf16x8 bfr = *(const bf16x8*)(Bp + ks * 32);
            a4 = __builtin_amdgcn_mfma_f32_16x16x32_bf16(af[ks], bfr, a4, 0, 0, 0);
        }
        float bv = gbias ? gbias[f] : 0.f;
#pragma unroll
        for (int rg = 0; rg < 4; rg++) {
            int node = wbase + quad * 4 + rg;
            if (node < NN) {
                float o = a4[rg];
                if (GSCALE) o *= dsc[rg];
                o += bv;
                if (OUT_BF16)
                    ((unsigned short*)gout)[(size_t)node * F + f] = f2bf(o);
                else
                    ((float*)gout)[(size_t)node * F + f] = o;
            }
        }
    }
}

// ---------------- host ----------------

extern "C" void kernel_launch(void* const* d_in, const int* in_sizes, int n_in,
                              void* d_out, int out_size, void* d_ws, size_t ws_size,
                              hipStream_t stream) {
    const float* x   = (const float*)d_in[0];
    const int*   ei  = (const int*)d_in[1];   // [2,E] int32
    const float* W1  = (const float*)d_in[2];
    const float* b1  = (const float*)d_in[3];
    const float* W2  = (const float*)d_in[4];
    const float* b2  = (const float*)d_in[5];
    const float* WL  = (const float*)d_in[6];
    const float* bl  = (const float*)d_in[7];
    float* out = (float*)d_out;

    const int* esrc = ei;
    const int* edst = ei + EE;

    char* w = (char*)d_ws;
    auto alloc = [&](size_t bytes) -> char* {
        char* p = w;
        w += (bytes + 255) & ~(size_t)255;
        return p;
    };
    int*   cntp    = (int*)alloc((size_t)NCOPY * NN * 4);  // 3.2MB XCD-local cursors
    int*   cnt     = (int*)alloc((size_t)NN * 4);
    int*   row_ptr = (int*)alloc((size_t)NN * 4);
    int2*  rc      = (int2*)alloc((size_t)NN * 8);
    float* dis     = (float*)alloc((size_t)NN * 4);
    int*   S       = (int*)alloc(1024 * 4);
    int*   rank    = (int*)alloc((size_t)EE * 4);
    int*   csr     = (int*)alloc((size_t)EE * 4);
    unsigned short* W1b = (unsigned short*)alloc(128 * 128 * 2);
    unsigned short* W2b = (unsigned short*)alloc(128 * 128 * 2);
    unsigned short* WLb = (unsigned short*)alloc(64 * 128 * 2);
    unsigned short* A   = (unsigned short*)alloc((size_t)(NN + 1) * 128 * 2);  // m1' + zero row
    unsigned short* A2  = (unsigned short*)alloc((size_t)(NN + 1) * 128 * 2);  // m2' + zero row
    unsigned short* B   = (unsigned short*)alloc((size_t)NN * 128 * 2);        // h1

    const int nb_e8 = (EE / 8 + 255) / 256;   // 782 == FB == count grid
    const int nb_s1 = (NN + 1023) / 1024;     // 98
    const int nb_s23 = (NN + 255) / 256;      // 391

    // init: zero cntp + weight converts (one packed launch)
    k_init<<<ZB + 40, 256, 0, stream>>>((int4*)cntp, W1, W2, WL, W1b, W2b, WLb);
    // rank histogram into XCD-local copies
    k_count_rank8<<<nb_e8, 256, 0, stream>>>(edst, cntp, rank);
    // copy-prefix + block scan; then fused S-scan + finalize (+zero rows of A/A2)
    k_scan1<<<nb_s1, 1024, 0, stream>>>(cntp, cnt, row_ptr, S);
    k_scan23<<<nb_s23, 256, 0, stream>>>(row_ptr, rc, S, nb_s1, cnt, dis, cntp,
                                         (unsigned int*)(A + (size_t)NN * 128),
                                         (unsigned int*)(A2 + (size_t)NN * 128));
    // packed: CSR place (no atomics) + GEMM1 (m1' = (x@W1.T)*dis) overlap
    k_pack1<<<FB + (NN + 63) / 64, 256, 0, stream>>>(esrc, edst, rank, cntp, csr,
                                                     x, W1b, dis, A);

    const int nb_agg = NN / 32;   // 3125, exact

    // layer 1: h1 = relu(dis*(sum+self)+b1)+x -> B(global)+LDS; m2' = (h1@W2.T)*dis -> A2
    k_aggemm<true, 128, true, true, true><<<nb_agg, 128, 0, stream>>>(
        A, rc, csr, dis, b1, x, B, W2b, nullptr, A2);
    // layer 2 + head: h2 = relu(dis*(sum+self)+b2)+h1 (LDS only); out = h2@WL.T+bl
    k_aggemm<false, 64, false, false, false><<<nb_agg, 128, 0, stream>>>(
        A2, rc, csr, dis, b2, B, nullptr, WLb, bl, out);
}

// Round 2
// 388.166 us; speedup vs baseline: 1.0584x; 1.0088x over previous
//
#include <hip/hip_runtime.h>

#define NN 100000
#define EE 1600000
#define NCOPY 8

typedef short bf16x8 __attribute__((ext_vector_type(8)));
typedef float floatx4 __attribute__((ext_vector_type(4)));

__device__ __forceinline__ unsigned short f2bf(float f) {
    unsigned int u = __float_as_uint(f);
    u = (u + 0x7FFF + ((u >> 16) & 1)) >> 16;   // round-to-nearest-even
    return (unsigned short)u;
}
__device__ __forceinline__ float bf2f_lo(unsigned int packed) {
    return __uint_as_float(packed << 16);
}
__device__ __forceinline__ float bf2f_hi(unsigned int packed) {
    return __uint_as_float(packed & 0xFFFF0000u);
}

// ---------------- init: zero cntp (782 blocks) + weight cvt (40 blocks) ------

#define ZB 782   // (NCOPY*NN/4 + 255)/256

__global__ __launch_bounds__(256) void k_init(int4* __restrict__ cntp4,
                                              const float* __restrict__ W1,
                                              const float* __restrict__ W2,
                                              const float* __restrict__ WL,
                                              unsigned short* __restrict__ W1b,
                                              unsigned short* __restrict__ W2b,
                                              unsigned short* __restrict__ WLb) {
    if (blockIdx.x < ZB) {
        int i = blockIdx.x * 256 + threadIdx.x;
        if (i < NCOPY * NN / 4) cntp4[i] = make_int4(0, 0, 0, 0);
        return;
    }
    int i = (blockIdx.x - ZB) * 256 + threadIdx.x;   // quad index
    const float* src; unsigned short* dst; int off;
    if (i < 4096)       { src = W1; dst = W1b; off = i; }
    else if (i < 8192)  { src = W2; dst = W2b; off = i - 4096; }
    else if (i < 10240) { src = WL; dst = WLb; off = i - 8192; }
    else return;
    float4 f = ((const float4*)src)[off];
    unsigned short r0 = f2bf(f.x), r1 = f2bf(f.y), r2 = f2bf(f.z), r3 = f2bf(f.w);
    ((ushort2*)dst)[off * 2]     = make_ushort2(r0, r1);
    ((ushort2*)dst)[off * 2 + 1] = make_ushort2(r2, r3);
}

// Pass 1: rank within XCD-local copy (p = blockIdx&7).
__global__ void k_count_rank8(const int* __restrict__ dst, int* __restrict__ cntp,
                              int* __restrict__ rank) {
    int e8 = (blockIdx.x * 256 + threadIdx.x) * 8;
    int* c = cntp + (blockIdx.x & (NCOPY - 1)) * NN;
    if (e8 < EE) {   // EE % 8 == 0
        int4 d0 = *(const int4*)&dst[e8];
        int4 d1 = *(const int4*)&dst[e8 + 4];
        int4 r0, r1;
        r0.x = atomicAdd(&c[d0.x], 1);
        r0.y = atomicAdd(&c[d0.y], 1);
        r0.z = atomicAdd(&c[d0.z], 1);
        r0.w = atomicAdd(&c[d0.w], 1);
        r1.x = atomicAdd(&c[d1.x], 1);
        r1.y = atomicAdd(&c[d1.y], 1);
        r1.z = atomicAdd(&c[d1.z], 1);
        r1.w = atomicAdd(&c[d1.w], 1);
        *(int4*)&rank[e8]     = r0;
        *(int4*)&rank[e8 + 4] = r1;
    }
}

// scan1: per-node copy-prefix across the 8 cntp copies + 1024-block exclusive
// scan of totals; block totals -> S.
__global__ __launch_bounds__(1024) void k_scan1(int* __restrict__ cntp,
                                                int* __restrict__ cnt,
                                                int* __restrict__ row_ptr,
                                                int* __restrict__ S) {
    __shared__ int sh[1024];
    int tid = threadIdx.x;
    int i = blockIdx.x * 1024 + tid;
    int v = 0;
    if (i < NN) {
        int s = 0;
#pragma unroll
        for (int p = 0; p < NCOPY; p++) {
            int t = cntp[p * NN + i];
            cntp[p * NN + i] = s;    // within-node prefix across copies
            s += t;
        }
        cnt[i] = s;
        v = s;
    }
    sh[tid] = v;
    __syncthreads();
    for (int off = 1; off < 1024; off <<= 1) {
        int t = (tid >= off) ? sh[tid - off] : 0;
        __syncthreads();
        sh[tid] += t;
        __syncthreads();
    }
    if (i < NN) row_ptr[i] = sh[tid] - v;       // exclusive
    if (tid == 1023) S[blockIdx.x] = sh[tid];   // block total
}

// scan2+scan3 fused: every block redundantly scans the 98 block totals in LDS,
// then finalizes rc/dis and folds absolute row_ptr into the 8 copy cursors.
__global__ __launch_bounds__(256) void k_scan23(const int* __restrict__ row_ptr,
                                                int2* __restrict__ rc,
                                                const int* __restrict__ Sraw, int nb,
                                                const int* __restrict__ cnt,
                                                float* __restrict__ dis,
                                                int* __restrict__ cntp,
                                                unsigned int* __restrict__ Azero,
                                                unsigned int* __restrict__ A2zero) {
    __shared__ int sh[128];
    int tid = threadIdx.x;
    int v = 0;
    if (tid < 128) {
        v = (tid < nb) ? Sraw[tid] : 0;
        sh[tid] = v;
    }
    __syncthreads();
    for (int off = 1; off < 128; off <<= 1) {
        int t = 0;
        if (tid < 128 && tid >= off) t = sh[tid - off];
        __syncthreads();
        if (tid < 128) sh[tid] += t;
        __syncthreads();
    }
    int excl = 0;
    if (tid < 128) excl = sh[tid] - v;
    __syncthreads();
    if (tid < 128) sh[tid] = excl;
    __syncthreads();

    int i = blockIdx.x * 256 + tid;
    if (i < NN) {
        int c = cnt[i];
        int r = row_ptr[i] + sh[i >> 10];
        rc[i] = make_int2(r, c);
        dis[i] = rsqrtf((float)(c + 1));
#pragma unroll
        for (int p = 0; p < NCOPY; p++) cntp[p * NN + i] += r;  // absolute base cursors
    }
    if (blockIdx.x == 0 && tid < 64) { Azero[tid] = 0; A2zero[tid] = 0; }  // zero rows
}

// ---------------- MFMA GEMM body (used by packed gemm1) ----------------------
// C[M,F] = A[M,128] @ W[F,128].T, optional row scale (folds dis[src] in).
// Layouts (learn_hip m89): A[m=lane&15][k=quad*8+j], B[n=lane&15][k=quad*8+j],
// C/D col=lane&15 row=quad*4+reg.

template <int F, bool A_F32, bool OUT_BF16, bool SCALE>
__device__ __forceinline__ void gemm_body(int blk, int tid,
                                          const void* __restrict__ A_,
                                          const unsigned short* __restrict__ Wb,
                                          const float* __restrict__ bias,
                                          const float* __restrict__ scale,
                                          void* __restrict__ Cout, int M) {
    int wave = tid >> 6, lane = tid & 63;
    int quad = lane >> 4, r16 = lane & 15;
    int node0 = blk * 64 + wave * 16;

    int arow = node0 + r16;
    if (arow >= M) arow = M - 1;                 // clamp read; stores guarded

    bf16x8 af[4];
    if (A_F32) {
        const float* Ap = (const float*)A_ + (size_t)arow * 128 + quad * 8;
#pragma unroll
        for (int ks = 0; ks < 4; ks++) {
            float4 x0 = *(const float4*)(Ap + ks * 32);
            float4 x1 = *(const float4*)(Ap + ks * 32 + 4);
            bf16x8 t;
            t[0] = (short)f2bf(x0.x); t[1] = (short)f2bf(x0.y);
            t[2] = (short)f2bf(x0.z); t[3] = (short)f2bf(x0.w);
            t[4] = (short)f2bf(x1.x); t[5] = (short)f2bf(x1.y);
            t[6] = (short)f2bf(x1.z); t[7] = (short)f2bf(x1.w);
            af[ks] = t;
        }
    } else {
        const unsigned short* Ap = (const unsigned short*)A_ + (size_t)arow * 128 + quad * 8;
#pragma unroll
        for (int ks = 0; ks < 4; ks++) af[ks] = *(const bf16x8*)(Ap + ks * 32);
    }

    float dsc[4];
#pragma unroll
    for (int rg = 0; rg < 4; rg++) {
        int node = node0 + quad * 4 + rg;
        dsc[rg] = SCALE ? scale[(node < M) ? node : (M - 1)] : 1.f;
    }

    constexpr int NFT = F / 16;
#pragma unroll
    for (int ft = 0; ft < NFT; ft++) {
        int f = ft * 16 + r16;
        const unsigned short* Bp = Wb + (size_t)f * 128 + quad * 8;
        floatx4 acc = {0.f, 0.f, 0.f, 0.f};
#pragma unroll
        for (int ks = 0; ks < 4; ks++) {
            bf16x8 bfr = *(const bf16x8*)(Bp + ks * 32);
            acc = __builtin_amdgcn_mfma_f32_16x16x32_bf16(af[ks], bfr, acc, 0, 0, 0);
        }
        float bv = bias ? bias[f] : 0.f;
#pragma unroll
        for (int rg = 0; rg < 4; rg++) {
            int node = node0 + quad * 4 + rg;
            if (node < M) {
                float o = acc[rg];
                if (SCALE) o *= dsc[rg];
                o += bv;
                if (OUT_BF16)
                    ((unsigned short*)Cout)[(size_t)node * F + f] = f2bf(o);
                else
                    ((float*)Cout)[(size_t)node * F + f] = o;
            }
        }
    }
}

// ---------------- packed: fill4 (blocks 0..781) + GEMM1 (rest) ---------------

#define FB 782   // fill blocks

__global__ __launch_bounds__(256) void k_pack1(const int* __restrict__ src,
                                               const int* __restrict__ dst,
                                               const int* __restrict__ rank,
                                               const int* __restrict__ cntp,
                                               int* __restrict__ csr,
                                               const float* __restrict__ x,
                                               const unsigned short* __restrict__ W1b,
                                               const float* __restrict__ dis,
                                               unsigned short* __restrict__ A) {
    if (blockIdx.x < FB) {
        int e8 = (blockIdx.x * 256 + threadIdx.x) * 8;
        const int* c = cntp + (blockIdx.x & (NCOPY - 1)) * NN;
        if (e8 < EE) {
            int4 s0 = *(const int4*)&src[e8];
            int4 s1 = *(const int4*)&src[e8 + 4];
            int4 d0 = *(const int4*)&dst[e8];
            int4 d1 = *(const int4*)&dst[e8 + 4];
            int4 r0 = *(const int4*)&rank[e8];
            int4 r1 = *(const int4*)&rank[e8 + 4];
            csr[c[d0.x] + r0.x] = s0.x;
            csr[c[d0.y] + r0.y] = s0.y;
            csr[c[d0.z] + r0.z] = s0.z;
            csr[c[d0.w] + r0.w] = s0.w;
            csr[c[d1.x] + r1.x] = s1.x;
            csr[c[d1.y] + r1.y] = s1.y;
            csr[c[d1.z] + r1.z] = s1.z;
            csr[c[d1.w] + r1.w] = s1.w;
        }
        return;
    }
    gemm_body<128, true, true, true>(blockIdx.x - FB, threadIdx.x, x, W1b,
                                     nullptr, dis, A, NN);
}

// ---------------- fused aggregation + GEMM -----------------------------------
// Block = 256 thr = 4 waves = 2 independent 16-node tiles (2 waves/tile).
// Phase A (per wave, 8 nodes as 2 batches of 4): lane-group g OWNS node vb+g.
// Its 16 lanes gather the node's csr rows 8-deep (8 uint4 in flight per lane,
// 128B) and accumulate their own feature-octet directly -- no cross-lane
// reduce, no keep-mask. csr index int4 loads are 16B-aligned (start rounded
// down, validity predicate (unsigned)(base+k-sh)<c) and prefetched one
// iteration ahead so they stay in flight behind the gathers. Batch tail uses
// all 64 lanes (4 nodes x 16 octets). h -> padded LDS tile (+ optional global).
// Phase B: __syncthreads, then each wave does half the F-tiles of the 16x128
// MFMA GEMM from LDS (m2' = h@W2.T*dis, or head out = h@WL.T+bl).

#define ACC8(r)                                         \
    do {                                                \
        acc[0] += bf2f_lo(r.x); acc[1] += bf2f_hi(r.x); \
        acc[2] += bf2f_lo(r.y); acc[3] += bf2f_hi(r.y); \
        acc[4] += bf2f_lo(r.z); acc[5] += bf2f_hi(r.z); \
        acc[6] += bf2f_lo(r.w); acc[7] += bf2f_hi(r.w); \
    } while (0)

template <bool RES_F32, int F, bool OUT_BF16, bool GSCALE, bool WRITE_H>
__global__ __launch_bounds__(256) void k_aggemm(const unsigned short* __restrict__ m,
                                                const int2* __restrict__ rc,
                                                const int* __restrict__ csr,
                                                const float* __restrict__ dis,
                                                const float* __restrict__ bias,
                                                const void* __restrict__ res_,
                                                unsigned short* __restrict__ hout,
                                                const unsigned short* __restrict__ Wb,
                                                const float* __restrict__ gbias,
                                                void* __restrict__ gout) {
    __shared__ unsigned short hsh[2][16][136];   // +8 pad: 2-way max on frag reads
    int tid = threadIdx.x;
    int w = tid >> 6, lane = tid & 63;
    int t = w >> 1, hf = w & 1;                  // tile, half
    int tile_base = blockIdx.x * 32 + t * 16;    // NN % 32 == 0: no guards
    int g = lane >> 4;                           // lane-group = node-in-batch
    int r16 = lane & 15;
    int fl = r16 * 8;                            // 8 features per lane
    const char* mb2 = (const char*)m + fl * 2;   // 32-bit row offsets: s<<8

    float4 q0 = *(const float4*)&bias[fl];
    float4 q1 = *(const float4*)&bias[fl + 4];
    float bb[8] = {q0.x, q0.y, q0.z, q0.w, q1.x, q1.y, q1.z, q1.w};

#pragma unroll
    for (int b = 0; b < 2; ++b) {
        int v = tile_base + hf * 8 + b * 4 + g;  // my group's node
        int2 rcv = rc[v];
        int start = rcv.x, c = rcv.y;
        int ab = start & ~3;                     // 16B-aligned csr base
        int sh0 = start - ab;                    // 0..3
        int cm = sh0 + c;                        // iterations cover [0, cm)
        cm = max(cm, __shfl_xor(cm, 16));
        cm = max(cm, __shfl_xor(cm, 32));        // wave-uniform bound

        float acc[8];
#pragma unroll
        for (int j = 0; j < 8; j++) acc[j] = 0.f;

        int4 ia = *(const int4*)&csr[ab];
        int4 ib = *(const int4*)&csr[ab + 4];
        for (int base = 0; base < cm; base += 8) {
            unsigned cc = (unsigned)c;
            int s0 = ((unsigned)(base + 0 - sh0) < cc) ? ia.x : NN;
            int s1 = ((unsigned)(base + 1 - sh0) < cc) ? ia.y : NN;
            int s2 = ((unsigned)(base + 2 - sh0) < cc) ? ia.z : NN;
            int s3 = ((unsigned)(base + 3 - sh0) < cc) ? ia.w : NN;
            int s4 = ((unsigned)(base + 4 - sh0) < cc) ? ib.x : NN;
            int s5 = ((unsigned)(base + 5 - sh0) < cc) ? ib.y : NN;
            int s6 = ((unsigned)(base + 6 - sh0) < cc) ? ib.z : NN;
            int s7 = ((unsigned)(base + 7 - sh0) < cc) ? ib.w : NN;
            uint4 r0 = *(const uint4*)(mb2 + (s0 << 8));
            uint4 r1 = *(const uint4*)(mb2 + (s1 << 8));
            uint4 r2 = *(const uint4*)(mb2 + (s2 << 8));
            uint4 r3 = *(const uint4*)(mb2 + (s3 << 8));
            uint4 r4 = *(const uint4*)(mb2 + (s4 << 8));
            uint4 r5 = *(const uint4*)(mb2 + (s5 << 8));
            uint4 r6 = *(const uint4*)(mb2 + (s6 << 8));
            uint4 r7 = *(const uint4*)(mb2 + (s7 << 8));
            ia = *(const int4*)&csr[ab + base + 8];    // prefetch next (stays in flight)
            ib = *(const int4*)&csr[ab + base + 12];
            ACC8(r0); ACC8(r1); ACC8(r2); ACC8(r3);
            ACC8(r4); ACC8(r5); ACC8(r6); ACC8(r7);
        }

        // batched tail: 64 lanes = 4 nodes x 16 feature-octets
        float dv = dis[v];
        uint4 mv = *(const uint4*)(m + (size_t)v * 128 + fl);
        float mvf[8] = {bf2f_lo(mv.x), bf2f_hi(mv.x), bf2f_lo(mv.y), bf2f_hi(mv.y),
                        bf2f_lo(mv.z), bf2f_hi(mv.z), bf2f_lo(mv.w), bf2f_hi(mv.w)};
        float rr[8];
        if (RES_F32) {
            const float* rp = (const float*)res_ + (size_t)v * 128 + fl;
            float4 a0 = *(const float4*)rp;
            float4 a1 = *(const float4*)(rp + 4);
            rr[0] = a0.x; rr[1] = a0.y; rr[2] = a0.z; rr[3] = a0.w;
            rr[4] = a1.x; rr[5] = a1.y; rr[6] = a1.z; rr[7] = a1.w;
        } else {
            uint4 rv = *(const uint4*)((const unsigned short*)res_ + (size_t)v * 128 + fl);
            rr[0] = bf2f_lo(rv.x); rr[1] = bf2f_hi(rv.x);
            rr[2] = bf2f_lo(rv.y); rr[3] = bf2f_hi(rv.y);
            rr[4] = bf2f_lo(rv.z); rr[5] = bf2f_hi(rv.z);
            rr[6] = bf2f_lo(rv.w); rr[7] = bf2f_hi(rv.w);
        }
        unsigned short po[8];
#pragma unroll
        for (int j = 0; j < 8; j++) {
            float sum = acc[j] + mvf[j];
            float tv = fmaxf(fmaf(sum, dv, bb[j]), 0.f) + rr[j];
            po[j] = f2bf(tv);
        }
        uint4 o;
        o.x = (unsigned)po[0] | ((unsigned)po[1] << 16);
        o.y = (unsigned)po[2] | ((unsigned)po[3] << 16);
        o.z = (unsigned)po[4] | ((unsigned)po[5] << 16);
        o.w = (unsigned)po[6] | ((unsigned)po[7] << 16);
        *(uint4*)&hsh[t][hf * 8 + b * 4 + g][fl] = o;
        if (WRITE_H) *(uint4*)&hout[(size_t)v * 128 + fl] = o;
    }

    __syncthreads();   // partner wave's 8 rows must land

    // Phase B: C[tile_base..+15][hf's half of F) = hsh[t] @ Wb.T (+scale/bias)
    int quad = g;
    bf16x8 af[4];
    const unsigned short* Ap = &hsh[t][r16][quad * 8];
#pragma unroll
    for (int ks = 0; ks < 4; ks++) af[ks] = *(const bf16x8*)(Ap + ks * 32);
    float dsc[4];
#pragma unroll
    for (int rg = 0; rg < 4; rg++) {
        int node = tile_base + quad * 4 + rg;
        dsc[rg] = GSCALE ? dis[node] : 1.f;
    }
    constexpr int NFT = F / 16, HFT = NFT / 2;
#pragma unroll
    for (int ftl = 0; ftl < HFT; ftl++) {
        int ft = hf * HFT + ftl;
        int f = ft * 16 + r16;
        const unsigned short* Bp = Wb + (size_t)f * 128 + quad * 8;
        floatx4 a4 = {0.f, 0.f, 0.f, 0.f};
#pragma unroll
        for (int ks = 0; ks < 4; ks++) {
            bf16x8 bfr = *(const bf16x8*)(Bp + ks * 32);
            a4 = __builtin_amdgcn_mfma_f32_16x16x32_bf16(af[ks], bfr, a4, 0, 0, 0);
        }
        float bv = gbias ? gbias[f] : 0.f;
#pragma unroll
        for (int rg = 0; rg < 4; rg++) {
            int node = tile_base + quad * 4 + rg;
            float o = a4[rg];
            if (GSCALE) o *= dsc[rg];
            o += bv;
            if (OUT_BF16)
                ((unsigned short*)gout)[(size_t)node * F + f] = f2bf(o);
            else
                ((float*)gout)[(size_t)node * F + f] = o;
        }
    }
}

// ---------------- host ----------------

extern "C" void kernel_launch(void* const* d_in, const int* in_sizes, int n_in,
                              void* d_out, int out_size, void* d_ws, size_t ws_size,
                              hipStream_t stream) {
    const float* x   = (const float*)d_in[0];
    const int*   ei  = (const int*)d_in[1];   // [2,E] int32
    const float* W1  = (const float*)d_in[2];
    const float* b1  = (const float*)d_in[3];
    const float* W2  = (const float*)d_in[4];
    const float* b2  = (const float*)d_in[5];
    const float* WL  = (const float*)d_in[6];
    const float* bl  = (const float*)d_in[7];
    float* out = (float*)d_out;

    const int* esrc = ei;
    const int* edst = ei + EE;

    char* w = (char*)d_ws;
    auto alloc = [&](size_t bytes) -> char* {
        char* p = w;
        w += (bytes + 255) & ~(size_t)255;
        return p;
    };
    int*   cntp    = (int*)alloc((size_t)NCOPY * NN * 4);  // 3.2MB XCD-local cursors
    int*   cnt     = (int*)alloc((size_t)NN * 4);
    int*   row_ptr = (int*)alloc((size_t)NN * 4);
    int2*  rc      = (int2*)alloc((size_t)NN * 8);
    float* dis     = (float*)alloc((size_t)NN * 4);
    int*   S       = (int*)alloc(1024 * 4);
    int*   rank    = (int*)alloc((size_t)EE * 4);
    int*   csr     = (int*)alloc((size_t)EE * 4 + 256);    // +slack for aligned prefetch
    unsigned short* W1b = (unsigned short*)alloc(128 * 128 * 2);
    unsigned short* W2b = (unsigned short*)alloc(128 * 128 * 2);
    unsigned short* WLb = (unsigned short*)alloc(64 * 128 * 2);
    unsigned short* A   = (unsigned short*)alloc((size_t)(NN + 1) * 128 * 2);  // m1' + zero row
    unsigned short* A2  = (unsigned short*)alloc((size_t)(NN + 1) * 128 * 2);  // m2' + zero row
    unsigned short* B   = (unsigned short*)alloc((size_t)NN * 128 * 2);        // h1

    const int nb_e8 = (EE / 8 + 255) / 256;   // 782 == FB == count grid
    const int nb_s1 = (NN + 1023) / 1024;     // 98
    const int nb_s23 = (NN + 255) / 256;      // 391

    // init: zero cntp + weight converts (one packed launch)
    k_init<<<ZB + 40, 256, 0, stream>>>((int4*)cntp, W1, W2, WL, W1b, W2b, WLb);
    // rank histogram into XCD-local copies
    k_count_rank8<<<nb_e8, 256, 0, stream>>>(edst, cntp, rank);
    // copy-prefix + block scan; then fused S-scan + finalize (+zero rows of A/A2)
    k_scan1<<<nb_s1, 1024, 0, stream>>>(cntp, cnt, row_ptr, S);
    k_scan23<<<nb_s23, 256, 0, stream>>>(row_ptr, rc, S, nb_s1, cnt, dis, cntp,
                                         (unsigned int*)(A + (size_t)NN * 128),
                                         (unsigned int*)(A2 + (size_t)NN * 128));
    // packed: CSR place (no atomics) + GEMM1 (m1' = (x@W1.T)*dis) overlap
    k_pack1<<<FB + (NN + 63) / 64, 256, 0, stream>>>(esrc, edst, rank, cntp, csr,
                                                     x, W1b, dis, A);

    const int nb_agg = NN / 32;   // 3125, exact (NN % 32 == 0)

    // layer 1: h1 = relu(dis*(sum+self)+b1)+x -> B(global)+LDS; m2' = (h1@W2.T)*dis -> A2
    k_aggemm<true, 128, true, true, true><<<nb_agg, 256, 0, stream>>>(
        A, rc, csr, dis, b1, x, B, W2b, nullptr, A2);
    // layer 2 + head: h2 = relu(dis*(sum+self)+b2)+h1 (LDS only); out = h2@WL.T+bl
    k_aggemm<false, 64, false, false, false><<<nb_agg, 256, 0, stream>>>(
        A2, rc, csr, dis, b2, B, nullptr, WLb, bl, out);
}